// Round 5
// baseline (218.336 us; speedup 1.0000x reference)
//
#include <hip/hip_runtime.h>

#define BB 2
#define LL 2048
#define EE 1024
#define HH 16
#define HDD 64

typedef __bf16 bf16x8 __attribute__((ext_vector_type(8)));
typedef float f32x4 __attribute__((ext_vector_type(4)));

__device__ __forceinline__ unsigned short f2bf(float f) {
  unsigned int x = __float_as_uint(f);
  return (unsigned short)((x + 0x7FFFu + ((x >> 16) & 1u)) >> 16);  // RNE
}

__device__ __forceinline__ float bf2f(unsigned short u) {
  return __uint_as_float((unsigned int)u << 16);
}

__device__ __forceinline__ void load_lds16(const void* g, void* l) {
  __builtin_amdgcn_global_load_lds(
      (const __attribute__((address_space(1))) void*)g,
      (__attribute__((address_space(3))) void*)l, 16, 0, 0);
}

// pack 8 fp32 -> bf16x8 (compiler emits v_cvt_pk_bf16_f32 pairs, RNE —
// numerically identical to f2bf)
__device__ __forceinline__ bf16x8 cvt8(float4 lo, float4 hi) {
  bf16x8 r;
  r[0] = (__bf16)lo.x; r[1] = (__bf16)lo.y; r[2] = (__bf16)lo.z; r[3] = (__bf16)lo.w;
  r[4] = (__bf16)hi.x; r[5] = (__bf16)hi.y; r[6] = (__bf16)hi.z; r[7] = (__bf16)hi.w;
  return r;
}

// ---------------- prelude ----------------------------------------------------
// R5: q/pe are no longer cast (gemm reads fp32 directly) -> prelude is just
// blocks 0..255  : column sums of key/value -> per-chunk partials (no atomics)
// blocks 256..511: cast fp32->bf16 of Wq, Wp (2 MB each as bf16, reread 32x)
#define SUMKV_BLOCKS 256
#define WCAST_BLOCKS 256
__global__ __launch_bounds__(256) void prelude_kernel(
    const float* __restrict__ wq, const float* __restrict__ wp,
    unsigned short* __restrict__ wq16, unsigned short* __restrict__ wp16,
    const float* __restrict__ key, const float* __restrict__ value,
    float* __restrict__ kpart, float* __restrict__ vpart) {
  if (blockIdx.x < SUMKV_BLOCKS) {
    int blk2 = blockIdx.x;                // (b, 128 chunks of 16 rows)
    int b = blk2 >> 7, ch = blk2 & 127;
    int tid = threadIdx.x;                // float4 index within E
    const float4* k4 = (const float4*)(key   + ((size_t)b * LL + ch * 16) * EE);
    const float4* v4 = (const float4*)(value + ((size_t)b * LL + ch * 16) * EE);
    float4 ak = make_float4(0.f, 0.f, 0.f, 0.f);
    float4 av = make_float4(0.f, 0.f, 0.f, 0.f);
#pragma unroll 8
    for (int i = 0; i < 16; i++) {
      float4 kk = k4[i * 256 + tid];
      float4 vv = v4[i * 256 + tid];
      ak.x += kk.x; ak.y += kk.y; ak.z += kk.z; ak.w += kk.w;
      av.x += vv.x; av.y += vv.y; av.z += vv.z; av.w += vv.w;
    }
    ((float4*)(kpart + ((size_t)b * 128 + ch) * EE))[tid] = ak;
    ((float4*)(vpart + ((size_t)b * 128 + ch) * EE))[tid] = av;
  } else {
    const int NW4 = EE * EE / 4;        // 262144 float4s each for wq, wp
    int t = (blockIdx.x - SUMKV_BLOCKS) * 256 + threadIdx.x;  // 0..65535
#pragma unroll
    for (int k2 = 0; k2 < 8; k2++) {
      int i = t + k2 * 65536;           // 0..524287 exactly
      const float* src = (i < NW4) ? wq : wp;
      unsigned short* dst = (i < NW4) ? wq16 : wp16;
      int off = (i < NW4) ? i : i - NW4;
      float4 v = ((const float4*)src)[off];
      ushort4 u;
      u.x = f2bf(v.x); u.y = f2bf(v.y); u.z = f2bf(v.z); u.w = f2bf(v.w);
      ((ushort4*)dst)[off] = u;
    }
  }
}

// ---------------- reduce: sum 128 partials per (b, e) ------------------------
// grid 16 blocks x 256: idx -> {k|v} x (b, e). 2 MB of L2 reads, sub-µs.
__global__ __launch_bounds__(256) void reduce_kernel(
    const float* __restrict__ kpart, const float* __restrict__ vpart,
    float* __restrict__ keysum, float* __restrict__ valsum) {
  int idx = blockIdx.x * 256 + threadIdx.x;   // 0..4095
  const float* src = (idx & 2048) ? vpart : kpart;
  float* dst = (idx & 2048) ? valsum : keysum;
  int be = idx & 2047;                        // b*EE + e
  int b = be >> 10, e = be & (EE - 1);
  float s = 0.f;
  for (int c = 0; c < 128; c++) s += src[((size_t)b * 128 + c) * EE + e];
  dst[be] = s;
}

// ---------------- project summed key/value: sum @ W.T + L*bias ---------------
// grid (BB*EE/4, 1, 2): one wave per output, 4096 waves total.
__global__ __launch_bounds__(256) void proj_kernel(
    const float* __restrict__ keysum, const float* __restrict__ valsum,
    const float* __restrict__ Wk, const float* __restrict__ bk,
    const float* __restrict__ Wv, const float* __restrict__ bv,
    float* __restrict__ Kproj, float* __restrict__ Vproj) {
  int wv = threadIdx.x >> 6, lane = threadIdx.x & 63;
  int idx = blockIdx.x * 4 + wv;          // [0, BB*EE)
  int b = idx >> 10, ep = idx & (EE - 1);
  const float* sum  = blockIdx.z ? valsum : keysum;
  const float* W    = blockIdx.z ? Wv : Wk;
  const float* bias = blockIdx.z ? bv : bk;
  float* outp       = blockIdx.z ? Vproj : Kproj;
  float acc = 0.f;
  for (int k = lane; k < EE; k += 64) acc += sum[b * EE + k] * W[ep * EE + k];
  for (int off = 32; off; off >>= 1) acc += __shfl_down(acc, off, 64);
  if (lane == 0) outp[b * EE + ep] = acc + (float)LL * bias[ep];
}

// ---------------- bf16 MFMA GEMM + fused w2 slice ----------------------------
// R5: A-operand (q / pe) read DIRECTLY from fp32 inputs with reg-staging +
// in-register bf16 cast + swizzled ds_write (T14). This removes the q16/pe16
// intermediates: no 16.8 MB cold-intermediate read (the invariant ~41 µs
// across R0/R2/R4 pointed at the cold fetch stream, not the K-loop).
// B (weights) stays bf16 via global_load_lds (reread 32x -> bf16 halves it).
// Sync: simple 2-phase double buffer (R4's counted vmcnt bought nothing).
// Swizzle: physical 16B slot s' = (s + (row>>1)) & 3 on both sides.
//   A write side: thread t stages rows {t>>2, 64+(t>>2)}, logical slot t&3,
//   physical slot asw = ((t&3) + ((t>>3)&3)) & 3   [(row>>1)&3 == (t>>3)&3].
//   Read side koff: ((lane>>4) + ((lane&15)>>1)) & 3  (invariant over i*16).
// grid (32, 8, 3): z=0 -> q proj (+bq); z=1 -> r proj + fused 16-row chunk
// sums; z=2 -> w2 slice: W2[b,h,e] = sum_d Vproj[b,h*64+d] * Wo[e, h*64+d]
__global__ __launch_bounds__(256, 2) void gemm_kernel(
    const float* __restrict__ qf, const unsigned short* __restrict__ wq16,
    const float* __restrict__ bq, unsigned short* __restrict__ qout,
    const float* __restrict__ pef, const unsigned short* __restrict__ wp16,
    unsigned short* __restrict__ rout, float* __restrict__ chunks,
    const float* __restrict__ Vproj, const float* __restrict__ Wo,
    float* __restrict__ W2) {
  const int tid = threadIdx.x;
  const int lane = tid & 63;
  const int wv = tid >> 6;

  if (blockIdx.z == 2) {
    // ---- w2 slice: 256 blocks = 1024 waves, 32 outputs per wave ----
    int bid = blockIdx.x + 32 * blockIdx.y;   // 0..255
    int wslot = bid * 4 + wv;                 // 0..1023
    int base = wslot * 32;                    // first output idx
    int b = base >> 14;
    int h = (base >> 10) & (HH - 1);
    int e0 = base & (EE - 1);                 // 32 outputs stay in one (b,h)
    float vp = Vproj[b * EE + h * HDD + lane];
    const float* wo = Wo + (size_t)e0 * EE + h * HDD + lane;
    for (int r = 0; r < 32; r++) {
      float acc = vp * wo[(size_t)r * EE];
      for (int off = 32; off; off >>= 1) acc += __shfl_down(acc, off, 64);
      if (lane == 0) W2[((size_t)b * HH + h) * EE + e0 + r] = acc;
    }
    return;
  }

  const int K = EE, N = EE;
  const float* Xf; const unsigned short* W; const float* bias;
  unsigned short* Out;
  if (blockIdx.z == 0) { Xf = qf;  W = wq16; bias = bq;      Out = qout; }
  else                 { Xf = pef; W = wp16; bias = nullptr; Out = rout; }

  __shared__ __align__(16) unsigned short As[2][128 * 32];  // 2 x 8 KB
  __shared__ __align__(16) unsigned short Bs[2][128 * 32];  // 2 x 8 KB

  const int wr = wv >> 1, wc = wv & 1;      // wave tile: 64(m) x 64(n)
  const int m0 = blockIdx.x * 128;
  const int n0 = blockIdx.y * 128;

  // ---- A reg-staging addresses (fp32 source, coalesced 32B/thread/row) ----
  const int ar0 = tid >> 2;                 // row in tile (also +64)
  const int asw = ((tid & 3) + ((tid >> 3) & 3)) & 3;   // physical slot
  const float* gAf = Xf + (size_t)(m0 + ar0) * K + (tid & 3) * 8;

  // ---- B staging via global_load_lds, source pre-swizzled ----
  const int srow = wv * 16 + (lane >> 2);
  const int s_src = ((lane & 3) - ((lane >> 3) & 3)) & 3;
  const unsigned short* gB = W + (size_t)(n0 + srow) * K + s_src * 8;

  f32x4 acc[4][4];
#pragma unroll
  for (int i = 0; i < 4; i++)
#pragma unroll
    for (int j = 0; j < 4; j++) acc[i][j] = (f32x4)0.0f;

  const int arow = wr * 64 + (lane & 15);
  const int brow = wc * 64 + (lane & 15);
  const int koff = (((lane >> 4) + ((lane & 15) >> 1)) & 3) * 8;

  float4 ra0, ra1, ra2, ra3;
#define ALOAD(T)                                                          \
  do {                                                                    \
    const float* p = gAf + (T) * 32;                                      \
    ra0 = *(const float4*)(p);                                            \
    ra1 = *(const float4*)(p + 4);                                        \
    ra2 = *(const float4*)(p + (size_t)64 * K);                           \
    ra3 = *(const float4*)(p + (size_t)64 * K + 4);                       \
  } while (0)
#define AWRITE(BI)                                                        \
  do {                                                                    \
    *(bf16x8*)&As[BI][ar0 * 32 + asw * 8]        = cvt8(ra0, ra1);        \
    *(bf16x8*)&As[BI][(64 + ar0) * 32 + asw * 8] = cvt8(ra2, ra3);        \
  } while (0)
#define BSTAGE(BI, T)                                                     \
  do {                                                                    \
    load_lds16(gB + (T) * 32,                  &Bs[BI][wv * 512]);        \
    load_lds16(gB + (T) * 32 + (size_t)64 * K, &Bs[BI][wv * 512 + 2048]); \
  } while (0)
#define COMPUTE(BI)                                                       \
  do {                                                                    \
    bf16x8 af[4], bf[4];                                                  \
    _Pragma("unroll") for (int i = 0; i < 4; i++)                         \
      af[i] = *(const bf16x8*)&As[BI][(arow + i * 16) * 32 + koff];       \
    _Pragma("unroll") for (int j = 0; j < 4; j++)                         \
      bf[j] = *(const bf16x8*)&Bs[BI][(brow + j * 16) * 32 + koff];       \
    _Pragma("unroll") for (int i = 0; i < 4; i++)                         \
    _Pragma("unroll") for (int j = 0; j < 4; j++)                         \
      acc[i][j] = __builtin_amdgcn_mfma_f32_16x16x32_bf16(af[i], bf[j],   \
                                                          acc[i][j], 0, 0, 0); \
  } while (0)

  ALOAD(0); BSTAGE(0, 0); AWRITE(0);
  __syncthreads();
  for (int t = 0; t < 32; ++t) {
    int cur = t & 1, nxt = cur ^ 1;
    if (t + 1 < 32) { ALOAD(t + 1); BSTAGE(nxt, t + 1); }
    COMPUTE(cur);
    if (t + 1 < 32) AWRITE(nxt);      // loads covered by the COMPUTE above
    __syncthreads();
  }
#undef ALOAD
#undef AWRITE
#undef BSTAGE
#undef COMPUTE

  // epilogue: C/D layout col=lane&15, row=(lane>>4)*4+g  [verified m89/m91]
  const int rbase = m0 + wr * 64 + (lane >> 4) * 4;
  const int cbase = n0 + wc * 64 + (lane & 15);
#pragma unroll
  for (int i = 0; i < 4; i++) {
#pragma unroll
    for (int j = 0; j < 4; j++) {
      int col = cbase + j * 16;
      float badd = bias ? bias[col] : 0.f;
#pragma unroll
      for (int g = 0; g < 4; g++) {
        int row = rbase + i * 16 + g;
        Out[(size_t)row * N + col] = f2bf(acc[i][j][g] + badd);
      }
    }
  }

  // fused scan stage-1 for the r projection: 16-row chunk column sums (fp32).
  // acc[i][*] spans rows [m0 + wr*64 + i*16, +16) -> one chunk per i.
  if (blockIdx.z == 1) {
    int b = m0 >> 11;
    int ch0 = ((m0 + wr * 64) & (LL - 1)) >> 4;   // 16-row chunk index
#pragma unroll
    for (int i = 0; i < 4; i++) {
#pragma unroll
      for (int j = 0; j < 4; j++) {
        float s = acc[i][j][0] + acc[i][j][1] + acc[i][j][2] + acc[i][j][3];
        s += __shfl_down(s, 32, 64);
        s += __shfl_down(s, 16, 64);
        if (lane < 16) {
          int col = n0 + wc * 64 + j * 16 + lane;
          chunks[((size_t)b * 128 + ch0 + i) * EE + col] = s;
        }
      }
    }
  }
}

// ---------------- fused scan + score ----------------------------------------
// P[m] = prefix of r rows (in registers).  D[m] = (q_{L-1-m}+V) . P[m]
// S1[p] = (q_p+U).Kproj + (q_p+V).P[L]     (per-head dots over 64 lanes)
// grid (4, 128, BB) = 1024 blocks; 16-row chunks; chunk prefix recomputed
// locally (1 MB chunks buffer is L2-resident).
__global__ __launch_bounds__(256) void scan2f_kernel(
    const unsigned short* __restrict__ qbuf, const unsigned short* __restrict__ rbuf,
    const float* __restrict__ chunks, const float* __restrict__ Kproj,
    const float* __restrict__ U, const float* __restrict__ V,
    float* __restrict__ S1, float* __restrict__ Dbuf) {
  int tid = threadIdx.x, lane = tid & 63;
  int hg = blockIdx.x, ch = blockIdx.y, b = blockIdx.z;
  int e = hg * 256 + tid;
  int h = hg * 4 + (tid >> 6);
  float pre = 0.f, tot = 0.f;
  for (int c = 0; c < 128; c++) {
    float cs = chunks[((size_t)b * 128 + c) * EE + e];
    tot += cs;
    if (c < ch) pre += cs;
  }
  float kp = Kproj[b * EE + e], Ue = U[e], Ve = V[e];
  float run = pre;                          // == P[ch*16][e]
  size_t hoff = ((size_t)b * HH + h) * LL;
#pragma unroll 4
  for (int i = 0; i < 16; i++) {
    int m = ch * 16 + i;
    int p = LL - 1 - m;
    float qv = bf2f(qbuf[((size_t)b * LL + p) * EE + e]);
    float rv = bf2f(rbuf[((size_t)b * LL + m) * EE + e]);
    float tq = qv + Ve;
    float d = tq * run;                     // run == P[m]
    float s = tq * tot + (qv + Ue) * kp;
#pragma unroll
    for (int off = 32; off; off >>= 1) {
      d += __shfl_down(d, off, 64);
      s += __shfl_down(s, off, 64);
    }
    if (lane == 0) { Dbuf[hoff + m] = d; S1[hoff + p] = s; }
    run += rv;
  }
}

// ---------------- output: out[b,p,:] = sum_h S[b,h,p]*W2[b,h,:] + bo ---------
// S[b,h,p] = (S1[p] - D[L-1-p] + D[L-2-p]) / 32
// 512 blocks x 8 rows; W2[b] slice cached in 64 VGPRs/thread (16 float4).
__global__ __launch_bounds__(256) void out_kernel(
    const float* __restrict__ S1, const float* __restrict__ Dbuf,
    const float* __restrict__ W2, const float* __restrict__ bo,
    float* __restrict__ out) {
  int row0 = blockIdx.x * 8;              // [0, BB*LL)
  int b = row0 >> 11, p0 = row0 & (LL - 1);
  int tid = threadIdx.x;
  __shared__ float sh[8][HH];
  if (tid < 128) {
    int rr = tid >> 4, h = tid & 15;
    int p = p0 + rr;
    size_t hoff = ((size_t)b * HH + h) * LL;
    float s1 = S1[hoff + p];
    float d1 = Dbuf[hoff + (LL - 1 - p)];
    float d2 = (p == LL - 1) ? 0.f : Dbuf[hoff + (LL - 2 - p)];
    sh[rr][h] = (s1 - d1 + d2) * (1.f / 32.f);
  }
  float4 w2r[HH];
#pragma unroll
  for (int h = 0; h < HH; h++)
    w2r[h] = ((const float4*)(W2 + ((size_t)b * HH + h) * EE))[tid];
  float4 bo4 = ((const float4*)bo)[tid];
  __syncthreads();
#pragma unroll
  for (int rr = 0; rr < 8; rr++) {
    float4 acc = bo4;
#pragma unroll
    for (int h = 0; h < HH; h++) {
      float s = sh[rr][h];
      acc.x += s * w2r[h].x; acc.y += s * w2r[h].y;
      acc.z += s * w2r[h].z; acc.w += s * w2r[h].w;
    }
    ((float4*)out)[(size_t)(row0 + rr) * 256 + tid] = acc;
  }
}

extern "C" void kernel_launch(void* const* d_in, const int* in_sizes, int n_in,
                              void* d_out, int out_size, void* d_ws, size_t ws_size,
                              hipStream_t stream) {
  const float* query = (const float*)d_in[0];
  const float* key   = (const float*)d_in[1];
  const float* value = (const float*)d_in[2];
  const float* pos   = (const float*)d_in[3];
  const float* Wq = (const float*)d_in[4];
  const float* bq = (const float*)d_in[5];
  const float* Wk = (const float*)d_in[6];
  const float* bk = (const float*)d_in[7];
  const float* Wv = (const float*)d_in[8];
  const float* bv = (const float*)d_in[9];
  const float* Wp = (const float*)d_in[10];
  const float* Wo = (const float*)d_in[11];
  const float* bo = (const float*)d_in[12];
  const float* U  = (const float*)d_in[13];
  const float* V  = (const float*)d_in[14];
  float* out = (float*)d_out;

  char* ws = (char*)d_ws;
  size_t o = 0;
  auto take = [&](size_t bytes) -> char* {
    char* p = ws + o;
    o += (bytes + 255) & ~(size_t)255;
    return p;
  };
  float* keysum = (float*)take(BB * EE * 4);
  float* valsum = (float*)take(BB * EE * 4);
  float* Kproj  = (float*)take(BB * EE * 4);
  float* Vproj  = (float*)take(BB * EE * 4);
  float* W2     = (float*)take((size_t)BB * HH * EE * 4);
  float* S1     = (float*)take((size_t)BB * HH * LL * 4);
  float* Dbuf   = (float*)take((size_t)BB * HH * LL * 4);
  float* chunks = (float*)take((size_t)BB * 128 * EE * 4);
  float* kpart  = (float*)take((size_t)BB * 128 * EE * 4);
  float* vpart  = (float*)take((size_t)BB * 128 * EE * 4);
  unsigned short* qbuf = (unsigned short*)take((size_t)BB * LL * EE * 2);
  unsigned short* rbuf = (unsigned short*)take((size_t)BB * LL * EE * 2);
  unsigned short* wq16 = (unsigned short*)take((size_t)EE * EE * 2);
  unsigned short* wp16 = (unsigned short*)take((size_t)EE * EE * 2);

  prelude_kernel<<<SUMKV_BLOCKS + WCAST_BLOCKS, 256, 0, stream>>>(
      Wq, Wp, wq16, wp16, key, value, kpart, vpart);
  reduce_kernel<<<dim3(16), 256, 0, stream>>>(kpart, vpart, keysum, valsum);
  proj_kernel<<<dim3(BB * EE / 4, 1, 2), 256, 0, stream>>>(
      keysum, valsum, Wk, bk, Wv, bv, Kproj, Vproj);
  gemm_kernel<<<dim3(BB * LL / 128, EE / 128, 3), 256, 0, stream>>>(
      query, wq16, bq, qbuf, pos, wp16, rbuf, chunks, Vproj, Wo, W2);
  scan2f_kernel<<<dim3(4, 128, BB), 256, 0, stream>>>(
      qbuf, rbuf, chunks, Kproj, U, V, S1, Dbuf);
  out_kernel<<<dim3(BB * LL / 8), 256, 0, stream>>>(S1, Dbuf, W2, bo, out);
}

// Round 6
// 207.738 us; speedup vs baseline: 1.0510x; 1.0510x over previous
//
#include <hip/hip_runtime.h>

#define BB 2
#define LL 2048
#define EE 1024
#define HH 16
#define HDD 64

typedef __bf16 bf16x8 __attribute__((ext_vector_type(8)));
typedef float f32x4 __attribute__((ext_vector_type(4)));

__device__ __forceinline__ unsigned short f2bf(float f) {
  unsigned int x = __float_as_uint(f);
  return (unsigned short)((x + 0x7FFFu + ((x >> 16) & 1u)) >> 16);  // RNE
}

__device__ __forceinline__ float bf2f(unsigned short u) {
  return __uint_as_float((unsigned int)u << 16);
}

__device__ __forceinline__ void load_lds16(const void* g, void* l) {
  __builtin_amdgcn_global_load_lds(
      (const __attribute__((address_space(1))) void*)g,
      (__attribute__((address_space(3))) void*)l, 16, 0, 0);
}

// ---------------- prelude ----------------------------------------------------
// blocks 0..255   : column sums of key/value -> per-chunk partials (no atomics)
// blocks 256..1535: grid-stride cast fp32->bf16 of q, pe, Wq, Wp
#define SUMKV_BLOCKS 256
#define CAST_BLOCKS 1280
#define CAST_STRIDE (CAST_BLOCKS * 256)   // 327680 float4s per sweep
__global__ __launch_bounds__(256) void prelude_kernel(
    const float* __restrict__ q, const float* __restrict__ pe,
    const float* __restrict__ wq, const float* __restrict__ wp,
    unsigned short* __restrict__ q16, unsigned short* __restrict__ pe16,
    unsigned short* __restrict__ wq16, unsigned short* __restrict__ wp16,
    const float* __restrict__ key, const float* __restrict__ value,
    float* __restrict__ kpart, float* __restrict__ vpart) {
  if (blockIdx.x < SUMKV_BLOCKS) {
    int blk2 = blockIdx.x;                // (b, 128 chunks of 16 rows)
    int b = blk2 >> 7, ch = blk2 & 127;
    int tid = threadIdx.x;                // float4 index within E
    const float4* k4 = (const float4*)(key   + ((size_t)b * LL + ch * 16) * EE);
    const float4* v4 = (const float4*)(value + ((size_t)b * LL + ch * 16) * EE);
    float4 ak = make_float4(0.f, 0.f, 0.f, 0.f);
    float4 av = make_float4(0.f, 0.f, 0.f, 0.f);
#pragma unroll 8
    for (int i = 0; i < 16; i++) {
      float4 kk = k4[i * 256 + tid];
      float4 vv = v4[i * 256 + tid];
      ak.x += kk.x; ak.y += kk.y; ak.z += kk.z; ak.w += kk.w;
      av.x += vv.x; av.y += vv.y; av.z += vv.z; av.w += vv.w;
    }
    ((float4*)(kpart + ((size_t)b * 128 + ch) * EE))[tid] = ak;
    ((float4*)(vpart + ((size_t)b * 128 + ch) * EE))[tid] = av;
  } else {
    const int NQ4 = BB * LL * EE / 4;   // 1048576 float4s each for q, pe
    const int NW4 = EE * EE / 4;        // 262144 each for wq, wp
    int t = (blockIdx.x - SUMKV_BLOCKS) * 256 + threadIdx.x;
    float4 v[8]; unsigned short* dst[8]; int off[8];
#pragma unroll
    for (int k = 0; k < 8; k++) {
      int i = t + k * CAST_STRIDE;      // total = 8*327680 = 2621440 exactly
      const float* src;
      if (i < NQ4)                { src = q;  dst[k] = q16;  off[k] = i; }
      else if (i < 2 * NQ4)       { src = pe; dst[k] = pe16; off[k] = i - NQ4; }
      else if (i < 2 * NQ4 + NW4) { src = wq; dst[k] = wq16; off[k] = i - 2 * NQ4; }
      else                        { src = wp; dst[k] = wp16; off[k] = i - 2 * NQ4 - NW4; }
      v[k] = ((const float4*)src)[off[k]];
    }
#pragma unroll
    for (int k = 0; k < 8; k++) {
      ushort4 u;
      u.x = f2bf(v[k].x); u.y = f2bf(v[k].y); u.z = f2bf(v[k].z); u.w = f2bf(v[k].w);
      ((ushort4*)dst[k])[off[k]] = u;
    }
  }
}

// ---------------- reduce: sum 128 partials per (b, e) ------------------------
// grid 16 blocks x 256: idx -> {k|v} x (b, e). 2 MB of L2 reads, sub-µs.
__global__ __launch_bounds__(256) void reduce_kernel(
    const float* __restrict__ kpart, const float* __restrict__ vpart,
    float* __restrict__ keysum, float* __restrict__ valsum) {
  int idx = blockIdx.x * 256 + threadIdx.x;   // 0..4095
  const float* src = (idx & 2048) ? vpart : kpart;
  float* dst = (idx & 2048) ? valsum : keysum;
  int be = idx & 2047;                        // b*EE + e
  int b = be >> 10, e = be & (EE - 1);
  float s = 0.f;
  for (int c = 0; c < 128; c++) s += src[((size_t)b * 128 + c) * EE + e];
  dst[be] = s;
}

// ---------------- project summed key/value: sum @ W.T + L*bias ---------------
// grid (BB*EE/4, 1, 2): one wave per output, 4096 waves total.
__global__ __launch_bounds__(256) void proj_kernel(
    const float* __restrict__ keysum, const float* __restrict__ valsum,
    const float* __restrict__ Wk, const float* __restrict__ bk,
    const float* __restrict__ Wv, const float* __restrict__ bv,
    float* __restrict__ Kproj, float* __restrict__ Vproj) {
  int wv = threadIdx.x >> 6, lane = threadIdx.x & 63;
  int idx = blockIdx.x * 4 + wv;          // [0, BB*EE)
  int b = idx >> 10, ep = idx & (EE - 1);
  const float* sum  = blockIdx.z ? valsum : keysum;
  const float* W    = blockIdx.z ? Wv : Wk;
  const float* bias = blockIdx.z ? bv : bk;
  float* outp       = blockIdx.z ? Vproj : Kproj;
  float acc = 0.f;
  for (int k = lane; k < EE; k += 64) acc += sum[b * EE + k] * W[ep * EE + k];
  for (int off = 32; off; off >>= 1) acc += __shfl_down(acc, off, 64);
  if (lane == 0) outp[b * EE + ep] = acc + (float)LL * bias[ep];
}

// ---------------- bf16 MFMA GEMM + fused w2 slice ----------------------------
// R6: EXACT R4 structure (best measured total). 128x128 block, 4 waves of
// 64x64; triple-buffered LDS + counted vmcnt(4); both-sides swizzle
// (physical 16B slot s' = (s + (row>>1)) & 3). Only addition: z=1 epilogue
// also emits 64-row COARSE sums (reuses the shuffle results; 1 extra store
// per j per wave) so scan2f's prefix needs 32+3 loads instead of 128.
// grid (32, 8, 3): z=0 -> q proj (+bq); z=1 -> r proj + fused chunk sums;
// z=2 -> w2 slice: W2[b,h,e] = sum_d Vproj[b,h*64+d] * Wo[e, h*64+d]
__global__ __launch_bounds__(256, 3) void gemm_kernel(
    const unsigned short* __restrict__ q16, const unsigned short* __restrict__ wq16,
    const float* __restrict__ bq, unsigned short* __restrict__ qout,
    const unsigned short* __restrict__ pe16, const unsigned short* __restrict__ wp16,
    unsigned short* __restrict__ rout, float* __restrict__ chunks,
    float* __restrict__ coarse,
    const float* __restrict__ Vproj, const float* __restrict__ Wo,
    float* __restrict__ W2) {
  const int tid = threadIdx.x;
  const int lane = tid & 63;
  const int wv = tid >> 6;

  if (blockIdx.z == 2) {
    // ---- w2 slice: 256 blocks = 1024 waves, 32 outputs per wave ----
    int bid = blockIdx.x + 32 * blockIdx.y;   // 0..255
    int wslot = bid * 4 + wv;                 // 0..1023
    int base = wslot * 32;                    // first output idx
    int b = base >> 14;
    int h = (base >> 10) & (HH - 1);
    int e0 = base & (EE - 1);                 // 32 outputs stay in one (b,h)
    float vp = Vproj[b * EE + h * HDD + lane];
    const float* wo = Wo + (size_t)e0 * EE + h * HDD + lane;
    for (int r = 0; r < 32; r++) {
      float acc = vp * wo[(size_t)r * EE];
      for (int off = 32; off; off >>= 1) acc += __shfl_down(acc, off, 64);
      if (lane == 0) W2[((size_t)b * HH + h) * EE + e0 + r] = acc;
    }
    return;
  }

  const int K = EE, N = EE;
  const unsigned short* X; const unsigned short* W; const float* bias;
  unsigned short* Out;
  if (blockIdx.z == 0) { X = q16;  W = wq16; bias = bq;      Out = qout; }
  else                 { X = pe16; W = wp16; bias = nullptr; Out = rout; }

  __shared__ __align__(16) unsigned short As[3][128 * 32];  // 3 x 8 KB
  __shared__ __align__(16) unsigned short Bs[3][128 * 32];  // 3 x 8 KB

  const int wr = wv >> 1, wc = wv & 1;      // wave tile: 64(m) x 64(n)
  const int m0 = blockIdx.x * 128;
  const int n0 = blockIdx.y * 128;

  // staging: lane l of wave wv -> LDS bytes wv*1024 + l*16 (linear); covers
  // rows {wv*16.., 64+wv*16..} of the [128 x 32] tile. Source column is
  // pre-permuted with the swizzle inverse (stays in the same 64B segment).
  const int srow = wv * 16 + (lane >> 2);
  const int s_src = ((lane & 3) - ((lane >> 3) & 3)) & 3;
  const unsigned short* gA = X + (size_t)(m0 + srow) * K + s_src * 8;
  const unsigned short* gB = W + (size_t)(n0 + srow) * K + s_src * 8;

  f32x4 acc[4][4];
#pragma unroll
  for (int i = 0; i < 4; i++)
#pragma unroll
    for (int j = 0; j < 4; j++) acc[i][j] = (f32x4)0.0f;

  const int arow = wr * 64 + (lane & 15);
  const int brow = wc * 64 + (lane & 15);
  // read-side swizzle: logical slot (lane>>4) sits at physical
  //   ((lane>>4) + (row>>1)) & 3 ; (row>>1)&3 == ((lane&15)>>1)&3 for all i.
  const int koff = (((lane >> 4) + ((lane & 15) >> 1)) & 3) * 8;

#define GSTAGE(BI, KK)                                                    \
  do {                                                                    \
    load_lds16(gA + (KK),                  &As[BI][wv * 512]);            \
    load_lds16(gA + (KK) + (size_t)64 * K, &As[BI][wv * 512 + 2048]);     \
    load_lds16(gB + (KK),                  &Bs[BI][wv * 512]);            \
    load_lds16(gB + (KK) + (size_t)64 * K, &Bs[BI][wv * 512 + 2048]);     \
  } while (0)
#define COMPUTE(BI)                                                       \
  do {                                                                    \
    bf16x8 af[4], bf[4];                                                  \
    _Pragma("unroll") for (int i = 0; i < 4; i++)                         \
      af[i] = *(const bf16x8*)&As[BI][(arow + i * 16) * 32 + koff];       \
    _Pragma("unroll") for (int j = 0; j < 4; j++)                         \
      bf[j] = *(const bf16x8*)&Bs[BI][(brow + j * 16) * 32 + koff];       \
    _Pragma("unroll") for (int i = 0; i < 4; i++)                         \
    _Pragma("unroll") for (int j = 0; j < 4; j++)                         \
      acc[i][j] = __builtin_amdgcn_mfma_f32_16x16x32_bf16(af[i], bf[j],   \
                                                          acc[i][j], 0, 0, 0); \
  } while (0)

  GSTAGE(0, 0);
  GSTAGE(1, 32);
  int c0 = 0, c1 = 1, c2 = 2;               // compute buf, in-flight, stage tgt
  for (int t = 0; t < 32; ++t) {
    if (t < 31) asm volatile("s_waitcnt vmcnt(4)" ::: "memory");
    else        asm volatile("s_waitcnt vmcnt(0)" ::: "memory");
    __builtin_amdgcn_s_barrier();
    __builtin_amdgcn_sched_barrier(0);
    if (t + 2 < 32) GSTAGE(c2, (t + 2) * 32);
    COMPUTE(c0);
    int tmp = c0; c0 = c1; c1 = c2; c2 = tmp;
  }
#undef GSTAGE
#undef COMPUTE

  // epilogue: C/D layout col=lane&15, row=(lane>>4)*4+g  [verified m89/m91]
  const int rbase = m0 + wr * 64 + (lane >> 4) * 4;
  const int cbase = n0 + wc * 64 + (lane & 15);
#pragma unroll
  for (int i = 0; i < 4; i++) {
#pragma unroll
    for (int j = 0; j < 4; j++) {
      int col = cbase + j * 16;
      float badd = bias ? bias[col] : 0.f;
#pragma unroll
      for (int g = 0; g < 4; g++) {
        int row = rbase + i * 16 + g;
        Out[(size_t)row * N + col] = f2bf(acc[i][j][g] + badd);
      }
    }
  }

  // fused scan stage-1 for the r projection: 16-row chunk column sums (fp32)
  // PLUS 64-row coarse sums (the wave's full row span). Shuffle results are
  // valid on lanes 0..15 (sum over the 4 row-groups for the same col).
  if (blockIdx.z == 1) {
    int b = m0 >> 11;
    int ch0 = ((m0 + wr * 64) & (LL - 1)) >> 4;   // 16-row chunk index
    int c64 = ((m0 + wr * 64) & (LL - 1)) >> 6;   // 64-row chunk index
#pragma unroll
    for (int j = 0; j < 4; j++) {
      float cs = 0.f;
#pragma unroll
      for (int i = 0; i < 4; i++) {
        float s = acc[i][j][0] + acc[i][j][1] + acc[i][j][2] + acc[i][j][3];
        s += __shfl_down(s, 32, 64);
        s += __shfl_down(s, 16, 64);
        cs += s;
        if (lane < 16) {
          int col = n0 + wc * 64 + j * 16 + lane;
          chunks[((size_t)b * 128 + ch0 + i) * EE + col] = s;
        }
      }
      if (lane < 16) {
        int col = n0 + wc * 64 + j * 16 + lane;
        coarse[((size_t)b * 32 + c64) * EE + col] = cs;
      }
    }
  }
}

// ---------------- fused scan + score ----------------------------------------
// P[m] = prefix of r rows (in registers).  D[m] = (q_{L-1-m}+V) . P[m]
// S1[p] = (q_p+U).Kproj + (q_p+V).P[L]     (per-head dots over 64 lanes)
// grid (4, 128, BB) = 1024 blocks; prefix/total from two-level chunk sums:
// 32 coarse (64-row) loads + <=3 fine (16-row) loads, vs 128 before.
__global__ __launch_bounds__(256) void scan2f_kernel(
    const unsigned short* __restrict__ qbuf, const unsigned short* __restrict__ rbuf,
    const float* __restrict__ chunks, const float* __restrict__ coarse,
    const float* __restrict__ Kproj,
    const float* __restrict__ U, const float* __restrict__ V,
    float* __restrict__ S1, float* __restrict__ Dbuf) {
  int tid = threadIdx.x, lane = tid & 63;
  int hg = blockIdx.x, ch = blockIdx.y, b = blockIdx.z;
  int e = hg * 256 + tid;
  int h = hg * 4 + (tid >> 6);
  float pre = 0.f, tot = 0.f;
  int c64lim = ch >> 2;
#pragma unroll
  for (int c = 0; c < 32; c++) {
    float cs = coarse[((size_t)b * 32 + c) * EE + e];
    tot += cs;
    if (c < c64lim) pre += cs;
  }
  for (int cf = ch & ~3; cf < ch; cf++)
    pre += chunks[((size_t)b * 128 + cf) * EE + e];
  float kp = Kproj[b * EE + e], Ue = U[e], Ve = V[e];
  float run = pre;                          // == P[ch*16][e]
  size_t hoff = ((size_t)b * HH + h) * LL;
#pragma unroll 4
  for (int i = 0; i < 16; i++) {
    int m = ch * 16 + i;
    int p = LL - 1 - m;
    float qv = bf2f(qbuf[((size_t)b * LL + p) * EE + e]);
    float rv = bf2f(rbuf[((size_t)b * LL + m) * EE + e]);
    float tq = qv + Ve;
    float d = tq * run;                     // run == P[m]
    float s = tq * tot + (qv + Ue) * kp;
#pragma unroll
    for (int off = 32; off; off >>= 1) {
      d += __shfl_down(d, off, 64);
      s += __shfl_down(s, off, 64);
    }
    if (lane == 0) { Dbuf[hoff + m] = d; S1[hoff + p] = s; }
    run += rv;
  }
}

// ---------------- output: out[b,p,:] = sum_h S[b,h,p]*W2[b,h,:] + bo ---------
// S[b,h,p] = (S1[p] - D[L-1-p] + D[L-2-p]) / 32
// R6: 256 blocks x 16 rows (halves W2 re-read traffic vs 8-row blocks).
__global__ __launch_bounds__(256) void out_kernel(
    const float* __restrict__ S1, const float* __restrict__ Dbuf,
    const float* __restrict__ W2, const float* __restrict__ bo,
    float* __restrict__ out) {
  int row0 = blockIdx.x * 16;             // [0, BB*LL)
  int b = row0 >> 11, p0 = row0 & (LL - 1);
  int tid = threadIdx.x;
  __shared__ float sh[16][HH];
  {
    int rr = tid >> 4, h = tid & 15;      // all 256 threads: 16 rows x 16 h
    int p = p0 + rr;
    size_t hoff = ((size_t)b * HH + h) * LL;
    float s1 = S1[hoff + p];
    float d1 = Dbuf[hoff + (LL - 1 - p)];
    float d2 = (p == LL - 1) ? 0.f : Dbuf[hoff + (LL - 2 - p)];
    sh[rr][h] = (s1 - d1 + d2) * (1.f / 32.f);
  }
  float4 w2r[HH];
#pragma unroll
  for (int h = 0; h < HH; h++)
    w2r[h] = ((const float4*)(W2 + ((size_t)b * HH + h) * EE))[tid];
  float4 bo4 = ((const float4*)bo)[tid];
  __syncthreads();
#pragma unroll
  for (int rr = 0; rr < 16; rr++) {
    float4 acc = bo4;
#pragma unroll
    for (int h = 0; h < HH; h++) {
      float s = sh[rr][h];
      acc.x += s * w2r[h].x; acc.y += s * w2r[h].y;
      acc.z += s * w2r[h].z; acc.w += s * w2r[h].w;
    }
    ((float4*)out)[(size_t)(row0 + rr) * 256 + tid] = acc;
  }
}

extern "C" void kernel_launch(void* const* d_in, const int* in_sizes, int n_in,
                              void* d_out, int out_size, void* d_ws, size_t ws_size,
                              hipStream_t stream) {
  const float* query = (const float*)d_in[0];
  const float* key   = (const float*)d_in[1];
  const float* value = (const float*)d_in[2];
  const float* pos   = (const float*)d_in[3];
  const float* Wq = (const float*)d_in[4];
  const float* bq = (const float*)d_in[5];
  const float* Wk = (const float*)d_in[6];
  const float* bk = (const float*)d_in[7];
  const float* Wv = (const float*)d_in[8];
  const float* bv = (const float*)d_in[9];
  const float* Wp = (const float*)d_in[10];
  const float* Wo = (const float*)d_in[11];
  const float* bo = (const float*)d_in[12];
  const float* U  = (const float*)d_in[13];
  const float* V  = (const float*)d_in[14];
  float* out = (float*)d_out;

  char* ws = (char*)d_ws;
  size_t o = 0;
  auto take = [&](size_t bytes) -> char* {
    char* p = ws + o;
    o += (bytes + 255) & ~(size_t)255;
    return p;
  };
  float* keysum = (float*)take(BB * EE * 4);
  float* valsum = (float*)take(BB * EE * 4);
  float* Kproj  = (float*)take(BB * EE * 4);
  float* Vproj  = (float*)take(BB * EE * 4);
  float* W2     = (float*)take((size_t)BB * HH * EE * 4);
  float* S1     = (float*)take((size_t)BB * HH * LL * 4);
  float* Dbuf   = (float*)take((size_t)BB * HH * LL * 4);
  float* chunks = (float*)take((size_t)BB * 128 * EE * 4);
  float* coarse = (float*)take((size_t)BB * 32 * EE * 4);
  float* kpart  = (float*)take((size_t)BB * 128 * EE * 4);
  float* vpart  = (float*)take((size_t)BB * 128 * EE * 4);
  unsigned short* qbuf = (unsigned short*)take((size_t)BB * LL * EE * 2);
  unsigned short* rbuf = (unsigned short*)take((size_t)BB * LL * EE * 2);
  unsigned short* q16  = (unsigned short*)take((size_t)BB * LL * EE * 2);
  unsigned short* pe16 = (unsigned short*)take((size_t)BB * LL * EE * 2);
  unsigned short* wq16 = (unsigned short*)take((size_t)EE * EE * 2);
  unsigned short* wp16 = (unsigned short*)take((size_t)EE * EE * 2);

  prelude_kernel<<<SUMKV_BLOCKS + CAST_BLOCKS, 256, 0, stream>>>(
      query, pos, Wq, Wp, q16, pe16, wq16, wp16, key, value, kpart, vpart);
  reduce_kernel<<<dim3(16), 256, 0, stream>>>(kpart, vpart, keysum, valsum);
  proj_kernel<<<dim3(BB * EE / 4, 1, 2), 256, 0, stream>>>(
      keysum, valsum, Wk, bk, Wv, bv, Kproj, Vproj);
  gemm_kernel<<<dim3(BB * LL / 128, EE / 128, 3), 256, 0, stream>>>(
      q16, wq16, bq, qbuf, pe16, wp16, rbuf, chunks, coarse, Vproj, Wo, W2);
  scan2f_kernel<<<dim3(4, 128, BB), 256, 0, stream>>>(
      qbuf, rbuf, chunks, coarse, Kproj, U, V, S1, Dbuf);
  out_kernel<<<dim3(BB * LL / 16), 256, 0, stream>>>(S1, Dbuf, W2, bo, out);
}